// Round 7
// baseline (264.369 us; speedup 1.0000x reference)
//
#include <hip/hip_runtime.h>

#define NND 20000
#define NE 200000
#define PDROP 0.1f

typedef unsigned short u16;
typedef __bf16 bf16x8 __attribute__((ext_vector_type(8)));
typedef float f32x4 __attribute__((ext_vector_type(4)));

__device__ __forceinline__ float b2f(u16 u) {
  unsigned v = ((unsigned)u) << 16;
  float f;
  __builtin_memcpy(&f, &v, 4);
  return f;
}
__device__ __forceinline__ u16 f2b(float f) {
  unsigned x;
  __builtin_memcpy(&x, &f, 4);
  unsigned r = x + 0x7fffu + ((x >> 16) & 1u);
  return (u16)(r >> 16);
}

__global__ void convert_x(const float* __restrict__ x, u16* __restrict__ xb) {
  int i = blockIdx.x * blockDim.x + threadIdx.x;
  if (i < NND * 256 / 4) {
    float4 v = ((const float4*)x)[i];
    ushort4 o;
    o.x = f2b(v.x); o.y = f2b(v.y); o.z = f2b(v.z); o.w = f2b(v.w);
    ((ushort4*)xb)[i] = o;
  }
}

// 0..3: Wq,Wk,Wv,Ws transposed; 4: We transposed (WeT); 5: We row-major (Web)
struct WTArgs {
  const float* W[6];
  u16* WT[6];
};
__global__ void convert_wT(WTArgs a) {
  int gid = blockIdx.x * blockDim.x + threadIdx.x;
  if (gid >= 6 * 65536) return;
  int w = gid >> 16, r = gid & 65535;
  if (w < 5) {
    int n = r >> 8, k = r & 255;
    a.WT[w][n * 256 + k] = f2b(a.W[w][k * 256 + n]);
  } else {
    a.WT[5][r] = f2b(a.W[5][r]);
  }
}

// ---- CSR build over dst ----
__global__ void zero2(int* __restrict__ cnt, int* __restrict__ cur) {
  int i = blockIdx.x * blockDim.x + threadIdx.x;
  if (i < NND) { cnt[i] = 0; cur[i] = 0; }
}
__global__ void csr_count(const int* __restrict__ ei, int* __restrict__ cnt) {
  int e = blockIdx.x * blockDim.x + threadIdx.x;
  if (e < NE) atomicAdd(&cnt[ei[NE + e]], 1);
}
__global__ __launch_bounds__(1024) void scan_rowptr(const int* __restrict__ cnt,
                                                    int* __restrict__ rowptr) {
  __shared__ int sums[1024];
  const int tid = threadIdx.x;
  const int base = tid * 20;
  int local[20];
  int run = 0;
#pragma unroll
  for (int i = 0; i < 20; i++) {
    int idx = base + i;
    local[i] = run;
    run += (idx < NND) ? cnt[idx] : 0;
  }
  sums[tid] = run;
  __syncthreads();
  for (int off = 1; off < 1024; off <<= 1) {
    int v = (tid >= off) ? sums[tid - off] : 0;
    __syncthreads();
    sums[tid] += v;
    __syncthreads();
  }
  int prev = (tid > 0) ? sums[tid - 1] : 0;
#pragma unroll
  for (int i = 0; i < 20; i++) {
    int idx = base + i;
    if (idx < NND) rowptr[idx] = prev + local[i];
  }
  if (tid == 1023) rowptr[NND] = sums[1023];
}
// fill elist + flattened per-slot edge records {src|keepbit, rel_t, wk0, wk1}
__global__ void csr_fill(const int* __restrict__ ei,
                         const float* __restrict__ last_update,
                         const float* __restrict__ t,
                         const float* __restrict__ u_edge,
                         const float* __restrict__ u_attn,
                         const int* __restrict__ rowptr, int* __restrict__ cur,
                         int* __restrict__ elist, uint4* __restrict__ recs) {
  int e = blockIdx.x * blockDim.x + threadIdx.x;
  if (e < NE) {
    int s = ei[e];
    int d = ei[NE + e];
    int p = rowptr[d] + atomicAdd(&cur[d], 1);
    elist[p] = e;
    bool keep = u_edge[e] > PDROP;
    float rt = last_update[s] - t[e];
    float2 ua = *(const float2*)&u_attn[(size_t)e * 2];
    uint4 r;
    r.x = (unsigned)s | (keep ? 0u : 0x80000000u);
    r.y = __float_as_uint(rt);
    r.z = __float_as_uint(ua.x > PDROP ? (1.f / 0.9f) : 0.f);
    r.w = __float_as_uint(ua.y > PDROP ? (1.f / 0.9f) : 0.f);
    recs[p] = r;
  }
}

// ---- shared MFMA compute: 4 waves, each 64x64 of a 128x128 tile ----
__device__ __forceinline__ void mfma_tile(const u16 (*As)[72], const u16 (*Bs)[72],
                                          f32x4 acc[4][4], int wm, int wn,
                                          int fr, int fg) {
#pragma unroll
  for (int ks = 0; ks < 2; ks++) {
    bf16x8 a[4], b[4];
#pragma unroll
    for (int i = 0; i < 4; i++)
      a[i] = *(const bf16x8*)&As[wm * 64 + i * 16 + fr][ks * 32 + fg * 8];
#pragma unroll
    for (int j = 0; j < 4; j++)
      b[j] = *(const bf16x8*)&Bs[wn * 64 + j * 16 + fr][ks * 32 + fg * 8];
#pragma unroll
    for (int i = 0; i < 4; i++)
#pragma unroll
      for (int j = 0; j < 4; j++)
        acc[i][j] = __builtin_amdgcn_mfma_f32_16x16x32_bf16(a[i], b[j], acc[i][j], 0, 0, 0);
  }
}

// ---- fused node GEMM: y in [0,8): w=y>>1 selects {Wq,Wk,Wv,Ws} ----
struct NodeArgs {
  const u16* BT[4];
  const float* bias[4];
  u16* outb[3];   // q, k, v (bf16)
  float* outf;    // skip -> d_out (f32)
};
__global__ __launch_bounds__(256) void gemm_node(const u16* __restrict__ xb,
                                                 NodeArgs args) {
  __shared__ __attribute__((aligned(16))) u16 As[128][72];
  __shared__ __attribute__((aligned(16))) u16 Bs[128][72];
  const int tid = threadIdx.x;
  const int w = blockIdx.y >> 1;
  const int col0 = (blockIdx.y & 1) * 128;
  const int row0 = blockIdx.x * 128;
  const u16* BT = args.BT[w];
  const float* bias = args.bias[w];
  const int wid = tid >> 6, lane = tid & 63;
  const int wm = wid >> 1, wn = wid & 1;
  const int fr = lane & 15, fg = lane >> 4;
  f32x4 acc[4][4] = {};
  for (int k0 = 0; k0 < 256; k0 += 64) {
#pragma unroll
    for (int i = 0; i < 4; i++) {
      int idx = tid + i * 256;
      int row = idx >> 3, vc = idx & 7;
      int g = row0 + row;
      uint4 v = make_uint4(0, 0, 0, 0);
      if (g < NND) v = *(const uint4*)&xb[(size_t)g * 256 + k0 + vc * 8];
      *(uint4*)&As[row][vc * 8] = v;
      *(uint4*)&Bs[row][vc * 8] = *(const uint4*)&BT[(size_t)(col0 + row) * 256 + k0 + vc * 8];
    }
    __syncthreads();
    mfma_tile(As, Bs, acc, wm, wn, fr, fg);
    __syncthreads();
  }
#pragma unroll
  for (int mi = 0; mi < 4; mi++) {
#pragma unroll
    for (int rr = 0; rr < 4; rr++) {
      int grow = row0 + wm * 64 + mi * 16 + fg * 4 + rr;
      if (grow >= NND) continue;
#pragma unroll
      for (int ni = 0; ni < 4; ni++) {
        int gcol = col0 + wn * 64 + ni * 16 + fr;
        float val = acc[mi][ni][rr] + bias[gcol];
        if (w < 3)
          args.outb[w][(size_t)grow * 256 + gcol] = f2b(val);
        else
          args.outf[(size_t)grow * 256 + gcol] = val;
      }
    }
  }
}

// ---- qWe GEMM: qWe[n,h,j] = sum_c We[j, h*128+c] * q[n, h*128+c] ----
__global__ __launch_bounds__(256) void gemm_qwe(const u16* __restrict__ qb,
                                                const u16* __restrict__ Web,
                                                u16* __restrict__ qWeb) {
  __shared__ __attribute__((aligned(16))) u16 As[128][72];
  __shared__ __attribute__((aligned(16))) u16 Bs[128][72];
  const int tid = threadIdx.x;
  const int h = blockIdx.y >> 1;
  const int col0 = (blockIdx.y & 1) * 128;
  const int row0 = blockIdx.x * 128;
  const int wid = tid >> 6, lane = tid & 63;
  const int wm = wid >> 1, wn = wid & 1;
  const int fr = lane & 15, fg = lane >> 4;
  f32x4 acc[4][4] = {};
  for (int k0 = 0; k0 < 128; k0 += 64) {
#pragma unroll
    for (int i = 0; i < 4; i++) {
      int idx = tid + i * 256;
      int row = idx >> 3, vc = idx & 7;
      int g = row0 + row;
      uint4 v = make_uint4(0, 0, 0, 0);
      if (g < NND) v = *(const uint4*)&qb[(size_t)g * 256 + h * 128 + k0 + vc * 8];
      *(uint4*)&As[row][vc * 8] = v;
      *(uint4*)&Bs[row][vc * 8] =
          *(const uint4*)&Web[(size_t)(col0 + row) * 256 + h * 128 + k0 + vc * 8];
    }
    __syncthreads();
    mfma_tile(As, Bs, acc, wm, wn, fr, fg);
    __syncthreads();
  }
#pragma unroll
  for (int mi = 0; mi < 4; mi++) {
#pragma unroll
    for (int rr = 0; rr < 4; rr++) {
      int grow = row0 + wm * 64 + mi * 16 + fg * 4 + rr;
      if (grow >= NND) continue;
#pragma unroll
      for (int ni = 0; ni < 4; ni++) {
        int gj = col0 + wn * 64 + ni * 16 + fr;
        qWeb[(size_t)grow * 512 + h * 256 + gj] = f2b(acc[mi][ni][rr]);
      }
    }
  }
}

// ---- fused per-node attention: single pass, online softmax, prefetch ----
__global__ __launch_bounds__(256) void node_fused(
    const u16* __restrict__ qb, const u16* __restrict__ kb,
    const u16* __restrict__ vb, const u16* __restrict__ qWeb,
    const float* __restrict__ msg, const float* __restrict__ tw,
    const float* __restrict__ tb_, const float* __restrict__ be,
    const int* __restrict__ rowptr, const int* __restrict__ elist,
    const uint4* __restrict__ recs, u16* __restrict__ aggb,
    float* __restrict__ out) {
  const int node = (blockIdx.x * blockDim.x + threadIdx.x) >> 6;
  const int lane = threadIdx.x & 63;
  if (node >= NND) return;
  const int beg = rowptr[node], end = rowptr[node + 1];
  const int c0 = lane * 4, hl = lane >> 5;

  // node-side loads (once)
  ushort4 q4 = *(const ushort4*)&qb[(size_t)node * 256 + c0];
  float qf0 = b2f(q4.x), qf1 = b2f(q4.y), qf2 = b2f(q4.z), qf3 = b2f(q4.w);
  ushort4 w0v = *(const ushort4*)&qWeb[(size_t)node * 512 + c0];
  ushort4 w1v = *(const ushort4*)&qWeb[(size_t)node * 512 + 256 + c0];
  float qw00 = b2f(w0v.x), qw01 = b2f(w0v.y), qw02 = b2f(w0v.z), qw03 = b2f(w0v.w);
  float qw10 = b2f(w1v.x), qw11 = b2f(w1v.y), qw12 = b2f(w1v.z), qw13 = b2f(w1v.w);
  float4 bev = *(const float4*)&be[c0];
  float pb = qf0 * bev.x + qf1 * bev.y + qf2 * bev.z + qf3 * bev.w;
#pragma unroll
  for (int off = 16; off; off >>= 1) pb += __shfl_xor(pb, off);  // per-head
  float tw0 = 0, tw1 = 0, tw2 = 0, tw3 = 0, tb0 = 0, tb1 = 0, tb2 = 0, tb3 = 0;
  if (c0 < 100) {
    float4 a = *(const float4*)&tw[c0];
    float4 b = *(const float4*)&tb_[c0];
    tw0 = a.x; tw1 = a.y; tw2 = a.z; tw3 = a.w;
    tb0 = b.x; tb1 = b.y; tb2 = b.z; tb3 = b.w;
  }
  const float inv = 0.08838834764831845f;  // 1/sqrt(128)

  // online-softmax state (per-head, redundant per lane)
  float m0 = -INFINITY, m1 = -INFINITY;
  float den0 = 0.f, den1 = 0.f, sw0 = 0.f, sw1 = 0.f;
  float vc0 = 0, vc1 = 0, vc2 = 0, vc3 = 0;
  float g00 = 0, g01 = 0, g02 = 0, g03 = 0;
  float g10 = 0, g11 = 0, g12 = 0, g13 = 0;

  // software-pipelined loop: prefetch depth 1
  unsigned seC = 0; float rtC = 0, wk0C = 0, wk1C = 0;
  ushort4 k4C = make_ushort4(0, 0, 0, 0), v4C = make_ushort4(0, 0, 0, 0);
  float4 mmC = make_float4(0, 0, 0, 0);

#define LOAD_SLOT(J, se, rt, w0_, w1_, k4, v4, mm)                        \
  {                                                                       \
    uint4 rr_ = recs[J];                                                  \
    se = rr_.x; rt = __uint_as_float(rr_.y);                              \
    w0_ = __uint_as_float(rr_.z); w1_ = __uint_as_float(rr_.w);           \
    int s_ = (int)(se & 0x7fffffffu);                                     \
    k4 = *(const ushort4*)&kb[(size_t)s_ * 256 + c0];                     \
    v4 = *(const ushort4*)&vb[(size_t)s_ * 256 + c0];                     \
    if (c0 >= 100) {                                                      \
      int eid_ = elist[J];                                                \
      mm = *(const float4*)&msg[(size_t)eid_ * 156 + (c0 - 100)];         \
    }                                                                     \
  }

  if (beg < end) LOAD_SLOT(beg, seC, rtC, wk0C, wk1C, k4C, v4C, mmC);

  for (int j = beg; j < end; ++j) {
    // prefetch next slot
    unsigned seN = 0; float rtN = 0, wk0N = 0, wk1N = 0;
    ushort4 k4N = make_ushort4(0, 0, 0, 0), v4N = make_ushort4(0, 0, 0, 0);
    float4 mmN = make_float4(0, 0, 0, 0);
    if (j + 1 < end) LOAD_SLOT(j + 1, seN, rtN, wk0N, wk1N, k4N, v4N, mmN);

    // compute with current slot
    float ea0, ea1, ea2, ea3;
    if (c0 < 100) {
      ea0 = __cosf(rtC * tw0 + tb0); ea1 = __cosf(rtC * tw1 + tb1);
      ea2 = __cosf(rtC * tw2 + tb2); ea3 = __cosf(rtC * tw3 + tb3);
    } else {
      ea0 = mmC.x; ea1 = mmC.y; ea2 = mmC.z; ea3 = mmC.w;
    }
    float pqk = qf0 * b2f(k4C.x) + qf1 * b2f(k4C.y) +
                qf2 * b2f(k4C.z) + qf3 * b2f(k4C.w);
    float pe0 = qw00 * ea0 + qw01 * ea1 + qw02 * ea2 + qw03 * ea3;
    float pe1 = qw10 * ea0 + qw11 * ea1 + qw12 * ea2 + qw13 * ea3;
    float y0 = pe0 + __shfl_xor(pe0, 32);
    float y1 = pe1 + __shfl_xor(pe1, 32);
    float z = (lane < 32) ? y0 : y1;
#pragma unroll
    for (int off = 16; off; off >>= 1) {
      z += __shfl_xor(z, off);
      pqk += __shfl_xor(pqk, off);
    }
    float a = (seC < 0x80000000u) ? (pqk + z + pb) * inv : -INFINITY;
    float aoth = __shfl_xor(a, 32);
    float a0 = (lane < 32) ? a : aoth;
    float a1 = (lane < 32) ? aoth : a;
    // online rescale (wave-uniform branches)
    if (a0 > m0) {
      float sc = (m0 > -1e30f) ? __expf(m0 - a0) : 0.f;
      den0 *= sc; sw0 *= sc;
      g00 *= sc; g01 *= sc; g02 *= sc; g03 *= sc;
      float scv = hl ? 1.f : sc;
      vc0 *= scv; vc1 *= scv; vc2 *= scv; vc3 *= scv;
      m0 = a0;
    }
    if (a1 > m1) {
      float sc = (m1 > -1e30f) ? __expf(m1 - a1) : 0.f;
      den1 *= sc; sw1 *= sc;
      g10 *= sc; g11 *= sc; g12 *= sc; g13 *= sc;
      float scv = hl ? sc : 1.f;
      vc0 *= scv; vc1 *= scv; vc2 *= scv; vc3 *= scv;
      m1 = a1;
    }
    float ex0 = (a0 > -1e30f) ? __expf(a0 - m0) : 0.f;
    float ex1 = (a1 > -1e30f) ? __expf(a1 - m1) : 0.f;
    den0 += ex0; den1 += ex1;
    float w0 = ex0 * wk0C;
    float w1 = ex1 * wk1C;
    float wv = hl ? w1 : w0;
    vc0 += wv * b2f(v4C.x); vc1 += wv * b2f(v4C.y);
    vc2 += wv * b2f(v4C.z); vc3 += wv * b2f(v4C.w);
    g00 += w0 * ea0; g01 += w0 * ea1; g02 += w0 * ea2; g03 += w0 * ea3;
    g10 += w1 * ea0; g11 += w1 * ea1; g12 += w1 * ea2; g13 += w1 * ea3;
    sw0 += w0; sw1 += w1;

    // rotate pipeline
    seC = seN; rtC = rtN; wk0C = wk0N; wk1C = wk1N;
    k4C = k4N; v4C = v4N; mmC = mmN;
  }
#undef LOAD_SLOT

  float rden0 = 1.f / (den0 + 1e-16f), rden1 = 1.f / (den1 + 1e-16f);
  float rv = hl ? rden1 : rden0;
  float swv = hl ? sw1 : sw0;
  float4 o = *(float4*)&out[(size_t)node * 256 + c0];
  o.x += (vc0 + swv * bev.x) * rv;
  o.y += (vc1 + swv * bev.y) * rv;
  o.z += (vc2 + swv * bev.z) * rv;
  o.w += (vc3 + swv * bev.w) * rv;
  *(float4*)&out[(size_t)node * 256 + c0] = o;
  ushort4 a0v, a1v;
  a0v.x = f2b(g00 * rden0); a0v.y = f2b(g01 * rden0);
  a0v.z = f2b(g02 * rden0); a0v.w = f2b(g03 * rden0);
  a1v.x = f2b(g10 * rden1); a1v.y = f2b(g11 * rden1);
  a1v.z = f2b(g12 * rden1); a1v.w = f2b(g13 * rden1);
  *(ushort4*)&aggb[(size_t)node * 256 + c0] = a0v;
  *(ushort4*)&aggb[(size_t)(NND + node) * 256 + c0] = a1v;
}

// ---- final GEMM: out[:, h*128 + c] += agg_h (Nx256) @ We_h (256x128) ----
__global__ __launch_bounds__(256) void gemm_final(const u16* __restrict__ aggb,
                                                  const u16* __restrict__ WeT,
                                                  float* __restrict__ out) {
  __shared__ __attribute__((aligned(16))) u16 As[128][72];
  __shared__ __attribute__((aligned(16))) u16 Bs[128][72];
  const int tid = threadIdx.x;
  const int h = blockIdx.y;
  const int row0 = blockIdx.x * 128;
  const u16* A = aggb + (size_t)h * NND * 256;
  const int wid = tid >> 6, lane = tid & 63;
  const int wm = wid >> 1, wn = wid & 1;
  const int fr = lane & 15, fg = lane >> 4;
  f32x4 acc[4][4] = {};
  for (int k0 = 0; k0 < 256; k0 += 64) {
#pragma unroll
    for (int i = 0; i < 4; i++) {
      int idx = tid + i * 256;
      int row = idx >> 3, vc = idx & 7;
      int g = row0 + row;
      uint4 v = make_uint4(0, 0, 0, 0);
      if (g < NND) v = *(const uint4*)&A[(size_t)g * 256 + k0 + vc * 8];
      *(uint4*)&As[row][vc * 8] = v;
      *(uint4*)&Bs[row][vc * 8] =
          *(const uint4*)&WeT[(size_t)(h * 128 + row) * 256 + k0 + vc * 8];
    }
    __syncthreads();
    mfma_tile(As, Bs, acc, wm, wn, fr, fg);
    __syncthreads();
  }
#pragma unroll
  for (int mi = 0; mi < 4; mi++) {
#pragma unroll
    for (int rr = 0; rr < 4; rr++) {
      int grow = row0 + wm * 64 + mi * 16 + fg * 4 + rr;
      if (grow >= NND) continue;
#pragma unroll
      for (int ni = 0; ni < 4; ni++) {
        int gcol = wn * 64 + ni * 16 + fr;
        out[(size_t)grow * 256 + h * 128 + gcol] += acc[mi][ni][rr];
      }
    }
  }
}

extern "C" void kernel_launch(void* const* d_in, const int* in_sizes, int n_in,
                              void* d_out, int out_size, void* d_ws, size_t ws_size,
                              hipStream_t stream) {
  const float* x = (const float*)d_in[0];
  const float* last_update = (const float*)d_in[1];
  const int* ei = (const int*)d_in[2];
  const float* t = (const float*)d_in[3];
  const float* msg = (const float*)d_in[4];
  const float* u_edge = (const float*)d_in[5];
  const float* u_attn = (const float*)d_in[6];
  const float* time_w = (const float*)d_in[7];
  const float* time_b = (const float*)d_in[8];
  const float* Wq = (const float*)d_in[9];
  const float* bq = (const float*)d_in[10];
  const float* Wk = (const float*)d_in[11];
  const float* bk = (const float*)d_in[12];
  const float* Wv = (const float*)d_in[13];
  const float* bv = (const float*)d_in[14];
  const float* We = (const float*)d_in[15];
  const float* be = (const float*)d_in[16];
  const float* Ws = (const float*)d_in[17];
  const float* bs = (const float*)d_in[18];
  float* out = (float*)d_out;

  char* ws = (char*)d_ws;
  u16* xb = (u16*)(ws + 0);                    // 10,240,000
  u16* WT0 = (u16*)(ws + 10240000);            // 786,432
  u16* qb = (u16*)(ws + 11026432);             // 10,240,000
  u16* kb = (u16*)(ws + 21266432);             // 10,240,000
  u16* vb = (u16*)(ws + 31506432);             // 10,240,000
  u16* qWeb = (u16*)(ws + 41746432);           // 20,480,000
  u16* aggb = (u16*)(ws + 62226432);           // 20,480,000
  uint4* recs = (uint4*)(ws + 82706432);       // 3,200,000
  int* cnt = (int*)(ws + 85906432);            // 80,000
  int* cur = (int*)(ws + 85986432);            // 80,000
  int* rowptr = (int*)(ws + 86066432);         // 80,016
  int* elist = (int*)(ws + 86146448);          // 800,000
  // total ~87 MB

  // CSR build
  zero2<<<(NND + 255) / 256, 256, 0, stream>>>(cnt, cur);
  csr_count<<<(NE + 255) / 256, 256, 0, stream>>>(ei, cnt);
  scan_rowptr<<<1, 1024, 0, stream>>>(cnt, rowptr);
  csr_fill<<<(NE + 255) / 256, 256, 0, stream>>>(ei, last_update, t, u_edge,
                                                 u_attn, rowptr, cur, elist,
                                                 recs);

  // precompute
  WTArgs wa;
  wa.W[0] = Wq; wa.W[1] = Wk; wa.W[2] = Wv; wa.W[3] = Ws; wa.W[4] = We; wa.W[5] = We;
  for (int i = 0; i < 6; i++) wa.WT[i] = WT0 + (size_t)i * 65536;
  convert_wT<<<(6 * 65536 + 255) / 256, 256, 0, stream>>>(wa);
  convert_x<<<(NND * 64 + 255) / 256, 256, 0, stream>>>(x, xb);

  // node projections (q,k,v bf16; skip f32 -> out)
  NodeArgs na;
  na.BT[0] = wa.WT[0]; na.BT[1] = wa.WT[1]; na.BT[2] = wa.WT[2]; na.BT[3] = wa.WT[3];
  na.bias[0] = bq; na.bias[1] = bk; na.bias[2] = bv; na.bias[3] = bs;
  na.outb[0] = qb; na.outb[1] = kb; na.outb[2] = vb;
  na.outf = out;
  dim3 gn((NND + 127) / 128, 8);
  gemm_node<<<gn, 256, 0, stream>>>(xb, na);

  // qWe[n,h,256]
  dim3 gq((NND + 127) / 128, 4);
  gemm_qwe<<<gq, 256, 0, stream>>>(qb, wa.WT[5], qWeb);

  // fused single-pass attention per node (prefetched)
  node_fused<<<(NND + 3) / 4, 256, 0, stream>>>(
      qb, kb, vb, qWeb, msg, time_w, time_b, be, rowptr, elist, recs, aggb,
      out);

  // out += agg_h @ We_h
  dim3 gf((NND + 127) / 128, 2);
  gemm_final<<<gf, 256, 0, stream>>>(aggb, wa.WT[4], out);
}

// Round 8
// 249.138 us; speedup vs baseline: 1.0611x; 1.0611x over previous
//
#include <hip/hip_runtime.h>

#define NND 20000
#define NE 200000
#define PDROP 0.1f

typedef unsigned short u16;
typedef __bf16 bf16x8 __attribute__((ext_vector_type(8)));
typedef float f32x4 __attribute__((ext_vector_type(4)));

__device__ __forceinline__ float b2f(u16 u) {
  unsigned v = ((unsigned)u) << 16;
  float f;
  __builtin_memcpy(&f, &v, 4);
  return f;
}
__device__ __forceinline__ u16 f2b(float f) {
  unsigned x;
  __builtin_memcpy(&x, &f, 4);
  unsigned r = x + 0x7fffu + ((x >> 16) & 1u);
  return (u16)(r >> 16);
}

__global__ void convert_x(const float* __restrict__ x, u16* __restrict__ xb) {
  int i = blockIdx.x * blockDim.x + threadIdx.x;
  if (i < NND * 256 / 4) {
    float4 v = ((const float4*)x)[i];
    ushort4 o;
    o.x = f2b(v.x); o.y = f2b(v.y); o.z = f2b(v.z); o.w = f2b(v.w);
    ((ushort4*)xb)[i] = o;
  }
}

// 0..3: Wq,Wk,Wv,Ws transposed; 4: We transposed (WeT); 5: We row-major (Web)
struct WTArgs {
  const float* W[6];
  u16* WT[6];
};
__global__ void convert_wT(WTArgs a) {
  int gid = blockIdx.x * blockDim.x + threadIdx.x;
  if (gid >= 6 * 65536) return;
  int w = gid >> 16, r = gid & 65535;
  if (w < 5) {
    int n = r >> 8, k = r & 255;
    a.WT[w][n * 256 + k] = f2b(a.W[w][k * 256 + n]);
  } else {
    a.WT[5][r] = f2b(a.W[5][r]);
  }
}

// ---- CSR build over dst ----
__global__ void zero2(int* __restrict__ cnt, int* __restrict__ cur) {
  int i = blockIdx.x * blockDim.x + threadIdx.x;
  if (i < NND) { cnt[i] = 0; cur[i] = 0; }
}
__global__ void csr_count(const int* __restrict__ ei, int* __restrict__ cnt) {
  int e = blockIdx.x * blockDim.x + threadIdx.x;
  if (e < NE) atomicAdd(&cnt[ei[NE + e]], 1);
}
__global__ __launch_bounds__(1024) void scan_rowptr(const int* __restrict__ cnt,
                                                    int* __restrict__ rowptr) {
  __shared__ int sums[1024];
  const int tid = threadIdx.x;
  const int base = tid * 20;
  int local[20];
  int run = 0;
#pragma unroll
  for (int i = 0; i < 20; i++) {
    int idx = base + i;
    local[i] = run;
    run += (idx < NND) ? cnt[idx] : 0;
  }
  sums[tid] = run;
  __syncthreads();
  for (int off = 1; off < 1024; off <<= 1) {
    int v = (tid >= off) ? sums[tid - off] : 0;
    __syncthreads();
    sums[tid] += v;
    __syncthreads();
  }
  int prev = (tid > 0) ? sums[tid - 1] : 0;
#pragma unroll
  for (int i = 0; i < 20; i++) {
    int idx = base + i;
    if (idx < NND) rowptr[idx] = prev + local[i];
  }
  if (tid == 1023) rowptr[NND] = sums[1023];
}
// fill elist + flattened per-slot edge records {src|keepbit, rel_t, wk0, wk1}
__global__ void csr_fill(const int* __restrict__ ei,
                         const float* __restrict__ last_update,
                         const float* __restrict__ t,
                         const float* __restrict__ u_edge,
                         const float* __restrict__ u_attn,
                         const int* __restrict__ rowptr, int* __restrict__ cur,
                         int* __restrict__ elist, uint4* __restrict__ recs) {
  int e = blockIdx.x * blockDim.x + threadIdx.x;
  if (e < NE) {
    int s = ei[e];
    int d = ei[NE + e];
    int p = rowptr[d] + atomicAdd(&cur[d], 1);
    elist[p] = e;
    bool keep = u_edge[e] > PDROP;
    float rt = last_update[s] - t[e];
    float2 ua = *(const float2*)&u_attn[(size_t)e * 2];
    uint4 r;
    r.x = (unsigned)s | (keep ? 0u : 0x80000000u);
    r.y = __float_as_uint(rt);
    r.z = __float_as_uint(ua.x > PDROP ? (1.f / 0.9f) : 0.f);
    r.w = __float_as_uint(ua.y > PDROP ? (1.f / 0.9f) : 0.f);
    recs[p] = r;
  }
}

// ---- shared MFMA compute: 4 waves, each 64x64 of a 128x128 tile ----
__device__ __forceinline__ void mfma_tile(const u16 (*As)[72], const u16 (*Bs)[72],
                                          f32x4 acc[4][4], int wm, int wn,
                                          int fr, int fg) {
#pragma unroll
  for (int ks = 0; ks < 2; ks++) {
    bf16x8 a[4], b[4];
#pragma unroll
    for (int i = 0; i < 4; i++)
      a[i] = *(const bf16x8*)&As[wm * 64 + i * 16 + fr][ks * 32 + fg * 8];
#pragma unroll
    for (int j = 0; j < 4; j++)
      b[j] = *(const bf16x8*)&Bs[wn * 64 + j * 16 + fr][ks * 32 + fg * 8];
#pragma unroll
    for (int i = 0; i < 4; i++)
#pragma unroll
      for (int j = 0; j < 4; j++)
        acc[i][j] = __builtin_amdgcn_mfma_f32_16x16x32_bf16(a[i], b[j], acc[i][j], 0, 0, 0);
  }
}

// ---- fused node GEMM: y in [0,8): w=y>>1 selects {Wq,Wk,Wv,Ws} ----
struct NodeArgs {
  const u16* BT[4];
  const float* bias[4];
  u16* outb[3];   // q, k, v (bf16)
  float* outf;    // skip -> d_out (f32)
};
__global__ __launch_bounds__(256) void gemm_node(const u16* __restrict__ xb,
                                                 NodeArgs args) {
  __shared__ __attribute__((aligned(16))) u16 As[128][72];
  __shared__ __attribute__((aligned(16))) u16 Bs[128][72];
  const int tid = threadIdx.x;
  const int w = blockIdx.y >> 1;
  const int col0 = (blockIdx.y & 1) * 128;
  const int row0 = blockIdx.x * 128;
  const u16* BT = args.BT[w];
  const float* bias = args.bias[w];
  const int wid = tid >> 6, lane = tid & 63;
  const int wm = wid >> 1, wn = wid & 1;
  const int fr = lane & 15, fg = lane >> 4;
  f32x4 acc[4][4] = {};
  for (int k0 = 0; k0 < 256; k0 += 64) {
#pragma unroll
    for (int i = 0; i < 4; i++) {
      int idx = tid + i * 256;
      int row = idx >> 3, vc = idx & 7;
      int g = row0 + row;
      uint4 v = make_uint4(0, 0, 0, 0);
      if (g < NND) v = *(const uint4*)&xb[(size_t)g * 256 + k0 + vc * 8];
      *(uint4*)&As[row][vc * 8] = v;
      *(uint4*)&Bs[row][vc * 8] = *(const uint4*)&BT[(size_t)(col0 + row) * 256 + k0 + vc * 8];
    }
    __syncthreads();
    mfma_tile(As, Bs, acc, wm, wn, fr, fg);
    __syncthreads();
  }
#pragma unroll
  for (int mi = 0; mi < 4; mi++) {
#pragma unroll
    for (int rr = 0; rr < 4; rr++) {
      int grow = row0 + wm * 64 + mi * 16 + fg * 4 + rr;
      if (grow >= NND) continue;
#pragma unroll
      for (int ni = 0; ni < 4; ni++) {
        int gcol = col0 + wn * 64 + ni * 16 + fr;
        float val = acc[mi][ni][rr] + bias[gcol];
        if (w < 3)
          args.outb[w][(size_t)grow * 256 + gcol] = f2b(val);
        else
          args.outf[(size_t)grow * 256 + gcol] = val;
      }
    }
  }
}

// ---- qWe GEMM: qWe[n,h,j] = sum_c We[j, h*128+c] * q[n, h*128+c] ----
__global__ __launch_bounds__(256) void gemm_qwe(const u16* __restrict__ qb,
                                                const u16* __restrict__ Web,
                                                u16* __restrict__ qWeb) {
  __shared__ __attribute__((aligned(16))) u16 As[128][72];
  __shared__ __attribute__((aligned(16))) u16 Bs[128][72];
  const int tid = threadIdx.x;
  const int h = blockIdx.y >> 1;
  const int col0 = (blockIdx.y & 1) * 128;
  const int row0 = blockIdx.x * 128;
  const int wid = tid >> 6, lane = tid & 63;
  const int wm = wid >> 1, wn = wid & 1;
  const int fr = lane & 15, fg = lane >> 4;
  f32x4 acc[4][4] = {};
  for (int k0 = 0; k0 < 128; k0 += 64) {
#pragma unroll
    for (int i = 0; i < 4; i++) {
      int idx = tid + i * 256;
      int row = idx >> 3, vc = idx & 7;
      int g = row0 + row;
      uint4 v = make_uint4(0, 0, 0, 0);
      if (g < NND) v = *(const uint4*)&qb[(size_t)g * 256 + h * 128 + k0 + vc * 8];
      *(uint4*)&As[row][vc * 8] = v;
      *(uint4*)&Bs[row][vc * 8] =
          *(const uint4*)&Web[(size_t)(col0 + row) * 256 + h * 128 + k0 + vc * 8];
    }
    __syncthreads();
    mfma_tile(As, Bs, acc, wm, wn, fr, fg);
    __syncthreads();
  }
#pragma unroll
  for (int mi = 0; mi < 4; mi++) {
#pragma unroll
    for (int rr = 0; rr < 4; rr++) {
      int grow = row0 + wm * 64 + mi * 16 + fg * 4 + rr;
      if (grow >= NND) continue;
#pragma unroll
      for (int ni = 0; ni < 4; ni++) {
        int gj = col0 + wn * 64 + ni * 16 + fr;
        qWeb[(size_t)grow * 512 + h * 256 + gj] = f2b(acc[mi][ni][rr]);
      }
    }
  }
}

// ---- fused per-node attention: chunk-of-4 edges, online softmax ----
__global__ __launch_bounds__(256) void node_fused(
    const u16* __restrict__ qb, const u16* __restrict__ kb,
    const u16* __restrict__ vb, const u16* __restrict__ qWeb,
    const float* __restrict__ msg, const float* __restrict__ tw,
    const float* __restrict__ tb_, const float* __restrict__ be,
    const int* __restrict__ rowptr, const int* __restrict__ elist,
    const uint4* __restrict__ recs, u16* __restrict__ aggb,
    float* __restrict__ out) {
  const int node = (blockIdx.x * blockDim.x + threadIdx.x) >> 6;
  const int lane = threadIdx.x & 63;
  if (node >= NND) return;
  const int beg = rowptr[node], end = rowptr[node + 1];
  const int c0 = lane * 4, hl = lane >> 5;

  // node-side loads (once)
  ushort4 q4 = *(const ushort4*)&qb[(size_t)node * 256 + c0];
  float qf0 = b2f(q4.x), qf1 = b2f(q4.y), qf2 = b2f(q4.z), qf3 = b2f(q4.w);
  ushort4 w0v = *(const ushort4*)&qWeb[(size_t)node * 512 + c0];
  ushort4 w1v = *(const ushort4*)&qWeb[(size_t)node * 512 + 256 + c0];
  float qw00 = b2f(w0v.x), qw01 = b2f(w0v.y), qw02 = b2f(w0v.z), qw03 = b2f(w0v.w);
  float qw10 = b2f(w1v.x), qw11 = b2f(w1v.y), qw12 = b2f(w1v.z), qw13 = b2f(w1v.w);
  float4 bev = *(const float4*)&be[c0];
  float pb = qf0 * bev.x + qf1 * bev.y + qf2 * bev.z + qf3 * bev.w;
#pragma unroll
  for (int off = 16; off; off >>= 1) pb += __shfl_xor(pb, off);  // per-head
  float tw0 = 0, tw1 = 0, tw2 = 0, tw3 = 0, tb0 = 0, tb1 = 0, tb2 = 0, tb3 = 0;
  if (c0 < 100) {
    float4 a = *(const float4*)&tw[c0];
    float4 b = *(const float4*)&tb_[c0];
    tw0 = a.x; tw1 = a.y; tw2 = a.z; tw3 = a.w;
    tb0 = b.x; tb1 = b.y; tb2 = b.z; tb3 = b.w;
  }
  const float inv = 0.08838834764831845f;  // 1/sqrt(128)

  // online-softmax state (per-head, redundant per lane)
  float m0 = -INFINITY, m1 = -INFINITY;
  float den0 = 0.f, den1 = 0.f, sw0 = 0.f, sw1 = 0.f;
  float vc0 = 0, vc1 = 0, vc2 = 0, vc3 = 0;
  float g00 = 0, g01 = 0, g02 = 0, g03 = 0;
  float g10 = 0, g11 = 0, g12 = 0, g13 = 0;

  for (int j0 = beg; j0 < end; j0 += 4) {
    // ---- load phase: 4 edges, all independent (4x MLP) ----
    float ea[4][4];
    unsigned se[4];
    float rt[4], wk0[4], wk1[4];
    ushort4 k4[4], v4[4];
#pragma unroll
    for (int e = 0; e < 4; ++e) {
      int j = j0 + e;
      int jc = (j < end) ? j : (end - 1);
      uint4 rr = recs[jc];
      bool valid = (j < end);
      se[e] = valid ? rr.x : 0xFFFFFFFFu;
      rt[e] = __uint_as_float(rr.y);
      wk0[e] = valid ? __uint_as_float(rr.z) : 0.f;
      wk1[e] = valid ? __uint_as_float(rr.w) : 0.f;
      int s_ = (int)(rr.x & 0x7fffffffu);
      k4[e] = *(const ushort4*)&kb[(size_t)s_ * 256 + c0];
      v4[e] = *(const ushort4*)&vb[(size_t)s_ * 256 + c0];
      if (c0 >= 100) {
        int eid = elist[jc];
        *(float4*)&ea[e][0] = *(const float4*)&msg[(size_t)eid * 156 + (c0 - 100)];
      }
    }
    if (c0 < 100) {
#pragma unroll
      for (int e = 0; e < 4; ++e) {
        ea[e][0] = __cosf(rt[e] * tw0 + tb0);
        ea[e][1] = __cosf(rt[e] * tw1 + tb1);
        ea[e][2] = __cosf(rt[e] * tw2 + tb2);
        ea[e][3] = __cosf(rt[e] * tw3 + tb3);
      }
    }
    // ---- dot-product partials ----
    float z[4], pq[4];
#pragma unroll
    for (int e = 0; e < 4; ++e) {
      pq[e] = qf0 * b2f(k4[e].x) + qf1 * b2f(k4[e].y) +
              qf2 * b2f(k4[e].z) + qf3 * b2f(k4[e].w);
      float pe0 = qw00 * ea[e][0] + qw01 * ea[e][1] + qw02 * ea[e][2] + qw03 * ea[e][3];
      float pe1 = qw10 * ea[e][0] + qw11 * ea[e][1] + qw12 * ea[e][2] + qw13 * ea[e][3];
      float y0 = pe0 + __shfl_xor(pe0, 32);
      float y1 = pe1 + __shfl_xor(pe1, 32);
      z[e] = (lane < 32) ? y0 : y1;
    }
    // 8 independent shuffle chains — latencies pipeline
#pragma unroll
    for (int off = 16; off; off >>= 1) {
#pragma unroll
      for (int e = 0; e < 4; ++e) {
        z[e] += __shfl_xor(z[e], off);
        pq[e] += __shfl_xor(pq[e], off);
      }
    }
    float a0[4], a1[4];
#pragma unroll
    for (int e = 0; e < 4; ++e) {
      float a = (se[e] < 0x80000000u) ? (pq[e] + z[e] + pb) * inv : -INFINITY;
      float aoth = __shfl_xor(a, 32);
      a0[e] = (lane < 32) ? a : aoth;
      a1[e] = (lane < 32) ? aoth : a;
    }
    // ---- chunk-level online softmax: one rescale per chunk ----
    float cm0 = fmaxf(fmaxf(a0[0], a0[1]), fmaxf(a0[2], a0[3]));
    float cm1 = fmaxf(fmaxf(a1[0], a1[1]), fmaxf(a1[2], a1[3]));
    if (cm0 > m0) {
      float sc = (m0 > -1e30f) ? __expf(m0 - cm0) : 0.f;
      den0 *= sc; sw0 *= sc;
      g00 *= sc; g01 *= sc; g02 *= sc; g03 *= sc;
      float scv = hl ? 1.f : sc;
      vc0 *= scv; vc1 *= scv; vc2 *= scv; vc3 *= scv;
      m0 = cm0;
    }
    if (cm1 > m1) {
      float sc = (m1 > -1e30f) ? __expf(m1 - cm1) : 0.f;
      den1 *= sc; sw1 *= sc;
      g10 *= sc; g11 *= sc; g12 *= sc; g13 *= sc;
      float scv = hl ? sc : 1.f;
      vc0 *= scv; vc1 *= scv; vc2 *= scv; vc3 *= scv;
      m1 = cm1;
    }
#pragma unroll
    for (int e = 0; e < 4; ++e) {
      float ex0 = (a0[e] > -1e30f) ? __expf(a0[e] - m0) : 0.f;
      float ex1 = (a1[e] > -1e30f) ? __expf(a1[e] - m1) : 0.f;
      den0 += ex0; den1 += ex1;
      float w0 = ex0 * wk0[e], w1 = ex1 * wk1[e];
      float wv = hl ? w1 : w0;
      vc0 += wv * b2f(v4[e].x); vc1 += wv * b2f(v4[e].y);
      vc2 += wv * b2f(v4[e].z); vc3 += wv * b2f(v4[e].w);
      g00 += w0 * ea[e][0]; g01 += w0 * ea[e][1];
      g02 += w0 * ea[e][2]; g03 += w0 * ea[e][3];
      g10 += w1 * ea[e][0]; g11 += w1 * ea[e][1];
      g12 += w1 * ea[e][2]; g13 += w1 * ea[e][3];
      sw0 += w0; sw1 += w1;
    }
  }

  float rden0 = 1.f / (den0 + 1e-16f), rden1 = 1.f / (den1 + 1e-16f);
  float rv = hl ? rden1 : rden0;
  float swv = hl ? sw1 : sw0;
  float4 o = *(float4*)&out[(size_t)node * 256 + c0];
  o.x += (vc0 + swv * bev.x) * rv;
  o.y += (vc1 + swv * bev.y) * rv;
  o.z += (vc2 + swv * bev.z) * rv;
  o.w += (vc3 + swv * bev.w) * rv;
  *(float4*)&out[(size_t)node * 256 + c0] = o;
  ushort4 a0v, a1v;
  a0v.x = f2b(g00 * rden0); a0v.y = f2b(g01 * rden0);
  a0v.z = f2b(g02 * rden0); a0v.w = f2b(g03 * rden0);
  a1v.x = f2b(g10 * rden1); a1v.y = f2b(g11 * rden1);
  a1v.z = f2b(g12 * rden1); a1v.w = f2b(g13 * rden1);
  *(ushort4*)&aggb[(size_t)node * 256 + c0] = a0v;
  *(ushort4*)&aggb[(size_t)(NND + node) * 256 + c0] = a1v;
}

// ---- final GEMM: out[:, h*128 + c] += agg_h (Nx256) @ We_h (256x128) ----
__global__ __launch_bounds__(256) void gemm_final(const u16* __restrict__ aggb,
                                                  const u16* __restrict__ WeT,
                                                  float* __restrict__ out) {
  __shared__ __attribute__((aligned(16))) u16 As[128][72];
  __shared__ __attribute__((aligned(16))) u16 Bs[128][72];
  const int tid = threadIdx.x;
  const int h = blockIdx.y;
  const int row0 = blockIdx.x * 128;
  const u16* A = aggb + (size_t)h * NND * 256;
  const int wid = tid >> 6, lane = tid & 63;
  const int wm = wid >> 1, wn = wid & 1;
  const int fr = lane & 15, fg = lane >> 4;
  f32x4 acc[4][4] = {};
  for (int k0 = 0; k0 < 256; k0 += 64) {
#pragma unroll
    for (int i = 0; i < 4; i++) {
      int idx = tid + i * 256;
      int row = idx >> 3, vc = idx & 7;
      int g = row0 + row;
      uint4 v = make_uint4(0, 0, 0, 0);
      if (g < NND) v = *(const uint4*)&A[(size_t)g * 256 + k0 + vc * 8];
      *(uint4*)&As[row][vc * 8] = v;
      *(uint4*)&Bs[row][vc * 8] =
          *(const uint4*)&WeT[(size_t)(h * 128 + row) * 256 + k0 + vc * 8];
    }
    __syncthreads();
    mfma_tile(As, Bs, acc, wm, wn, fr, fg);
    __syncthreads();
  }
#pragma unroll
  for (int mi = 0; mi < 4; mi++) {
#pragma unroll
    for (int rr = 0; rr < 4; rr++) {
      int grow = row0 + wm * 64 + mi * 16 + fg * 4 + rr;
      if (grow >= NND) continue;
#pragma unroll
      for (int ni = 0; ni < 4; ni++) {
        int gcol = wn * 64 + ni * 16 + fr;
        out[(size_t)grow * 256 + h * 128 + gcol] += acc[mi][ni][rr];
      }
    }
  }
}

extern "C" void kernel_launch(void* const* d_in, const int* in_sizes, int n_in,
                              void* d_out, int out_size, void* d_ws, size_t ws_size,
                              hipStream_t stream) {
  const float* x = (const float*)d_in[0];
  const float* last_update = (const float*)d_in[1];
  const int* ei = (const int*)d_in[2];
  const float* t = (const float*)d_in[3];
  const float* msg = (const float*)d_in[4];
  const float* u_edge = (const float*)d_in[5];
  const float* u_attn = (const float*)d_in[6];
  const float* time_w = (const float*)d_in[7];
  const float* time_b = (const float*)d_in[8];
  const float* Wq = (const float*)d_in[9];
  const float* bq = (const float*)d_in[10];
  const float* Wk = (const float*)d_in[11];
  const float* bk = (const float*)d_in[12];
  const float* Wv = (const float*)d_in[13];
  const float* bv = (const float*)d_in[14];
  const float* We = (const float*)d_in[15];
  const float* be = (const float*)d_in[16];
  const float* Ws = (const float*)d_in[17];
  const float* bs = (const float*)d_in[18];
  float* out = (float*)d_out;

  char* ws = (char*)d_ws;
  u16* xb = (u16*)(ws + 0);                    // 10,240,000
  u16* WT0 = (u16*)(ws + 10240000);            // 786,432
  u16* qb = (u16*)(ws + 11026432);             // 10,240,000
  u16* kb = (u16*)(ws + 21266432);             // 10,240,000
  u16* vb = (u16*)(ws + 31506432);             // 10,240,000
  u16* qWeb = (u16*)(ws + 41746432);           // 20,480,000
  u16* aggb = (u16*)(ws + 62226432);           // 20,480,000
  uint4* recs = (uint4*)(ws + 82706432);       // 3,200,000
  int* cnt = (int*)(ws + 85906432);            // 80,000
  int* cur = (int*)(ws + 85986432);            // 80,000
  int* rowptr = (int*)(ws + 86066432);         // 80,016
  int* elist = (int*)(ws + 86146448);          // 800,000
  // total ~87 MB

  // CSR build
  zero2<<<(NND + 255) / 256, 256, 0, stream>>>(cnt, cur);
  csr_count<<<(NE + 255) / 256, 256, 0, stream>>>(ei, cnt);
  scan_rowptr<<<1, 1024, 0, stream>>>(cnt, rowptr);
  csr_fill<<<(NE + 255) / 256, 256, 0, stream>>>(ei, last_update, t, u_edge,
                                                 u_attn, rowptr, cur, elist,
                                                 recs);

  // precompute
  WTArgs wa;
  wa.W[0] = Wq; wa.W[1] = Wk; wa.W[2] = Wv; wa.W[3] = Ws; wa.W[4] = We; wa.W[5] = We;
  for (int i = 0; i < 6; i++) wa.WT[i] = WT0 + (size_t)i * 65536;
  convert_wT<<<(6 * 65536 + 255) / 256, 256, 0, stream>>>(wa);
  convert_x<<<(NND * 64 + 255) / 256, 256, 0, stream>>>(x, xb);

  // node projections (q,k,v bf16; skip f32 -> out)
  NodeArgs na;
  na.BT[0] = wa.WT[0]; na.BT[1] = wa.WT[1]; na.BT[2] = wa.WT[2]; na.BT[3] = wa.WT[3];
  na.bias[0] = bq; na.bias[1] = bk; na.bias[2] = bv; na.bias[3] = bs;
  na.outb[0] = qb; na.outb[1] = kb; na.outb[2] = vb;
  na.outf = out;
  dim3 gn((NND + 127) / 128, 8);
  gemm_node<<<gn, 256, 0, stream>>>(xb, na);

  // qWe[n,h,256]
  dim3 gq((NND + 127) / 128, 4);
  gemm_qwe<<<gq, 256, 0, stream>>>(qb, wa.WT[5], qWeb);

  // fused attention per node (chunk-of-4 edges)
  node_fused<<<(NND + 3) / 4, 256, 0, stream>>>(
      qb, kb, vb, qWeb, msg, time_w, time_b, be, rowptr, elist, recs, aggb,
      out);

  // out += agg_h @ We_h
  dim3 gf((NND + 127) / 128, 2);
  gemm_final<<<gf, 256, 0, stream>>>(aggb, wa.WT[4], out);
}